// Round 6
// baseline (79.161 us; speedup 1.0000x reference)
//
#include <hip/hip_runtime.h>
#include <math.h>

#define HW    4096
#define NC    32
#define NB    8
#define TINV  10.0f            // 1/TEMP
#define RWIN  8                // window radius; missed sources need |of|>5.5
#define WDIM  (8 + 2 * RWIN)   // 24
#define NSRC  (WDIM * WDIM)    // 576
#define RCUT  2.5f             // rect cut; excluded normalized weight < 1e-7

// One fused dispatch. grid (64 tiles, 2 ch-halves, 8 batches), 256 thr.
// LDS: XW[16ch][576 cells] staged x-window (reused as reduction buffer),
//      plds[576] params, per-wave survivor lists.
__global__ __launch_bounds__(256) void fused_kernel(
    const float* __restrict__ x, const float* __restrict__ of,
    float* __restrict__ out)
{
    __shared__ float  XW[16 * NSRC];    // 36864 B; overlaid by red later
    __shared__ float4 plds[NSRC];       //  9216 B
    __shared__ float4 wp[4][64];        //  4096 B
    __shared__ int    sc[4][64];        //  1024 B   -> 51.2 KB, 3 blocks/CU

    const int b    = blockIdx.z;
    const int h    = blockIdx.y;        // channel half
    const int tile = blockIdx.x;
    const int ty0  = (tile >> 3) << 3;
    const int tx0  = (tile & 7) << 3;
    const int tid  = threadIdx.x;

    // ---- Phase A: window params (oy, ox, 1/Dy, 1/Dx) ----
    for (int s = tid; s < NSRC; s += 256) {
        int sy = s / WDIM;
        int sx = s - sy * WDIM;
        int jy = ty0 - RWIN + sy;
        int jx = tx0 - RWIN + sx;
        float4 p = make_float4(0.f, 0.f, 0.f, 0.f);   // izy==0 marks invalid
        if ((unsigned)jy < 64u && (unsigned)jx < 64u) {
            int j = (jy << 6) + jx;
            float oy = (float)jy + of[(b * 2 + 0) * HW + j];
            float ox = (float)jx + of[(b * 2 + 1) * HW + j];
            int cy0 = min(max((int)floorf(oy), 0), 63);
            int cx0 = min(max((int)floorf(ox), 0), 63);
            float Dy = 0.f, Dx = 0.f;   // truncated denom: rel err < e^-25
            #pragma unroll
            for (int d = -3; d <= 3; ++d) {
                int iy = cy0 + d, ix = cx0 + d;
                if ((unsigned)iy < 64u) Dy += __expf(-TINV * fabsf(oy - (float)iy));
                if ((unsigned)ix < 64u) Dx += __expf(-TINV * fabsf(ox - (float)ix));
            }
            p = make_float4(oy, ox, 1.f / Dy, 1.f / Dx);
        }
        plds[s] = p;
    }

    // ---- Phase B: stage x[b, h*16+ch, window] -> XW[ch][cell] ----
    // float4 slots: 16 ch x 24 rows x 6 col-quads; 4-aligned so each quad is
    // all-valid or all-invalid (invalid cells are never read later)
    const float* xbase = x + (((b * NC + h * 16) << 12));
    for (int L = tid; L < 16 * 24 * 6; L += 256) {
        int ch  = L / 144;
        int rem = L - ch * 144;
        int row = rem / 6;
        int c4  = rem - row * 6;
        int jy  = ty0 - RWIN + row;
        int jx  = tx0 - RWIN + (c4 << 2);
        if ((unsigned)jy < 64u && (unsigned)jx < 64u) {
            float4 v = *(const float4*)(xbase + (ch << 12) + (jy << 6) + jx);
            *(float4*)(XW + ch * NSRC + row * WDIM + (c4 << 2)) = v;
        }
    }
    __syncthreads();

    // ---- Phase C: screen + gather (all memory is LDS) ----
    const int lane = tid & 63;
    const int wv   = __builtin_amdgcn_readfirstlane(tid >> 6);
    const float iy = (float)(ty0 + (lane >> 3));
    const float ix = (float)(tx0 + (lane & 7));

    float acc[16];
    #pragma unroll
    for (int c = 0; c < 16; ++c) acc[c] = 0.f;

    const int srow = lane >> 5;         // 2 window rows x 32 cols per round
    const int scol = lane & 31;

    for (int r = 0; r < 3; ++r) {
        int ry   = wv + srow * 4 + r * 8;        // all 24 rows over 4 waves
        bool lv  = (scol < WDIM);
        int cell = ry * WDIM + scol;
        float4 p = plds[lv ? cell : 0];
        float cy = fminf(fmaxf(p.x, 0.f), 63.f);
        float cx = fminf(fmaxf(p.y, 0.f), 63.f);
        float dyr = fmaxf(fmaxf((float)ty0 - cy, cy - ((float)ty0 + 7.f)), 0.f);
        float dxr = fmaxf(fmaxf((float)tx0 - cx, cx - ((float)tx0 + 7.f)), 0.f);
        bool pred = lv && (p.z != 0.f) && (dyr + dxr < RCUT);

        unsigned long long m = __ballot(pred);
        int cnt = __popcll(m);
        if (pred) {
            int pos = __builtin_amdgcn_mbcnt_hi((unsigned)(m >> 32),
                      __builtin_amdgcn_mbcnt_lo((unsigned)m, 0u));
            wp[wv][pos] = p;
            sc[wv][pos] = cell;
        }

        // survivor list, 2-wide; x from LDS broadcast reads (pipelinable)
        for (int k = 0; k < cnt; k += 2) {
            int i1 = min(k + 1, cnt - 1);
            float4 p0 = wp[wv][k], p1 = wp[wv][i1];
            int c0 = sc[wv][k], c1 = sc[wv][i1];

            float a0[16], a1[16];
            #pragma unroll
            for (int u = 0; u < 16; ++u) a0[u] = XW[u * NSRC + c0];
            #pragma unroll
            for (int u = 0; u < 16; ++u) a1[u] = XW[u * NSRC + c1];

            // per-dim normalize before product (fp32 overflow safety, OOB)
            float g0 = (__expf(-TINV * fabsf(p0.x - iy)) * p0.z)
                     * (__expf(-TINV * fabsf(p0.y - ix)) * p0.w);
            float g1 = (__expf(-TINV * fabsf(p1.x - iy)) * p1.z)
                     * (__expf(-TINV * fabsf(p1.y - ix)) * p1.w);
            g1 = (k + 1 < cnt) ? g1 : 0.f;

            #pragma unroll
            for (int u = 0; u < 16; ++u) acc[u] = fmaf(g0, a0[u], acc[u]);
            #pragma unroll
            for (int u = 0; u < 16; ++u) acc[u] = fmaf(g1, a1[u], acc[u]);
        }
    }

    // ---- Phase D: cross-wave reduction; red overlays XW (XW reads done) ----
    __syncthreads();
    float* red = XW;                    // 4*64*17 = 4352 floats <= 9216
    float* myred = red + (wv * 64 + lane) * 17;
    #pragma unroll
    for (int c = 0; c < 16; ++c) myred[c] = acc[c];
    __syncthreads();

    int c   = tid >> 4;                 // 0..15
    int t16 = tid & 15;
    #pragma unroll
    for (int k = 0; k < 4; ++k) {
        int t = t16 + 16 * k;
        float s = red[(0 * 64 + t) * 17 + c]
                + red[(1 * 64 + t) * 17 + c]
                + red[(2 * 64 + t) * 17 + c]
                + red[(3 * 64 + t) * 17 + c];
        int ch = h * 16 + c;
        out[(((b << 5) + ch) << 12) + (ty0 + (t >> 3)) * 64 + (tx0 + (t & 7))] = s;
    }
}

extern "C" void kernel_launch(void* const* d_in, const int* in_sizes, int n_in,
                              void* d_out, int out_size, void* d_ws, size_t ws_size,
                              hipStream_t stream) {
    const float* x  = (const float*)d_in[0];   // [8,32,64,64]
    const float* of = (const float*)d_in[1];   // [8,2,64,64]
    float* out = (float*)d_out;                // [8,32,64,64] fp32
    (void)d_ws; (void)ws_size;

    fused_kernel<<<dim3(64, 2, NB), dim3(256), 0, stream>>>(x, of, out);
}